// Round 9
// baseline (165.896 us; speedup 1.0000x reference)
//
#include <hip/hip_runtime.h>
#include <hip/hip_bf16.h>

// C = triu( triu(A) @ triu(B) ), N=4096, fp32 in/out.
// Split-K bf16 MFMA, KSTEP=64, LDS double-buffer, ONE barrier per step,
// 2-DEEP register prefetch: write_tiles(t+1) consumes loads issued at t-1,
// so the vmcnt wait is covered by a full step of compute (T4/T14).
// Sub-blocks grouped by shared A-panel (bi,ch), bj innermost, + chunked XCD
// swizzle. Kernel 1 zeroes C; kernel 2 accumulates with fp32 atomics.

#define NDIM 4096
#define BM 128
#define BN 128
#define KSTEP 64
#define NBLK (NDIM / BM)                  // 32
#define NSUB 1000                         // sum over tiles of ceil(L/8)
#define LSTR 144                          // 128B k-data + 16B pad per row/col
#define TILEB (BM * LSTR)                 // 18432 B per tile

typedef __attribute__((ext_vector_type(8))) short short8;
typedef __attribute__((ext_vector_type(4))) float f32x4;

__device__ __forceinline__ int loff(int row, int kb) {
    return row * LSTR + kb;   // kb = byte offset within the 128B row data
}

// packed fp32x2 -> bf16x2 (RNE) -- compiler emits v_cvt_pk_bf16_f32
__device__ __forceinline__ unsigned pkbf(float a, float b) {
    __hip_bfloat162 h = __float22bfloat162_rn(make_float2(a, b));
    unsigned r;
    __builtin_memcpy(&r, &h, sizeof(r));
    return r;
}

__global__ __launch_bounds__(256) void zero_c_kernel(float* __restrict__ C) {
    const float4 z = make_float4(0.f, 0.f, 0.f, 0.f);
    const size_t total = (size_t)NDIM * NDIM / 4;
    for (size_t i = blockIdx.x * 256 + threadIdx.x; i < total;
         i += (size_t)gridDim.x * 256)
        reinterpret_cast<float4*>(C)[i] = z;
}

__global__ __launch_bounds__(256, 2) void trimm_split_kernel(
    const float* __restrict__ A, const float* __restrict__ B,
    float* __restrict__ C) {
    const int tid = threadIdx.x;

    // ---- chunked XCD swizzle: contiguous logical ids -> same XCD ----
    const int logical = (blockIdx.x & 7) * (NSUB / 8) + (blockIdx.x >> 3);

    // ---- decode logical id -> (bi, ch, bj); groups share A panel ----
    int bi, ch = 0, bj = 0;
    {
        int r = logical;
        for (bi = 0; bi < NBLK; ++bi) {
            bool found = false;
            for (ch = 0;; ++ch) {
                const int c = NBLK - bi - 8 * ch;   // # bj sharing (bi,ch)
                if (c <= 0) break;
                if (r < c) { bj = bi + 8 * ch + r; found = true; break; }
                r -= c;
            }
            if (found) break;
        }
    }

    const int row0 = bi * BM;
    const int col0 = bj * BN;
    const int kstart = row0 + ch * 1024;
    const int kend = min(col0 + BN, kstart + 1024);
    const int nt = (kend - kstart) / KSTEP;   // 1..16 steps

    __shared__ __align__(16) char lds[2][2 * TILEB];  // 73728 B total

    f32x4 acc[4][4];
    const f32x4 fz = {0.f, 0.f, 0.f, 0.f};
#pragma unroll
    for (int m = 0; m < 4; ++m)
#pragma unroll
        for (int n = 0; n < 4; ++n) acc[m][n] = fz;

    const int wv = tid >> 6;
    const int wr = (wv >> 1) * 64;
    const int wc = (wv & 1) * 64;
    const int lane = tid & 63;
    const int fr = lane & 15;
    const int kb = (lane >> 4) * 16;

    // A staging: thread owns 8 f32x4 chunks; f = tid+256j ->
    //   row = f>>4 (16 chunks per 64-float row), LDS byte = (f&15)*8
    int arow[8], abyt[8];
#pragma unroll
    for (int j = 0; j < 8; ++j) {
        const int f = tid + 256 * j;
        arow[j] = f >> 4;
        abyt[j] = (f & 15) * 8;
    }
    // B staging: thread owns cols {2p, 2p+1}, k-quarter kq..kq+15
    const int cp = (tid & 63) * 2;
    const int kq = (tid >> 6) * 16;

    auto load_t = [&](f32x4* pa, float2* pb, int kt) {
#pragma unroll
        for (int j = 0; j < 8; ++j)
            pa[j] = *reinterpret_cast<const f32x4*>(
                &A[(size_t)(row0 + arow[j]) * NDIM + kt + (abyt[j] >> 1)]);
#pragma unroll
        for (int i = 0; i < 16; ++i)
            pb[i] = *reinterpret_cast<const float2*>(
                &B[(size_t)(kt + kq + i) * NDIM + col0 + cp]);
    };
    auto write_t = [&](char* base, const f32x4* pa, const float2* pb) {
        char* lA = base;
        char* lB = base + TILEB;
#pragma unroll
        for (int j = 0; j < 8; ++j) {
            uint2 w;
            w.x = pkbf(pa[j][0], pa[j][1]);
            w.y = pkbf(pa[j][2], pa[j][3]);
            *reinterpret_cast<uint2*>(lA + loff(arow[j], abyt[j])) = w;
        }
#pragma unroll
        for (int c = 0; c < 2; ++c) {
            uint4 w0, w1;
            const float2* p = pb;
            if (c == 0) {
                w0.x = pkbf(p[0].x, p[1].x);  w0.y = pkbf(p[2].x, p[3].x);
                w0.z = pkbf(p[4].x, p[5].x);  w0.w = pkbf(p[6].x, p[7].x);
                w1.x = pkbf(p[8].x, p[9].x);  w1.y = pkbf(p[10].x, p[11].x);
                w1.z = pkbf(p[12].x, p[13].x); w1.w = pkbf(p[14].x, p[15].x);
            } else {
                w0.x = pkbf(p[0].y, p[1].y);  w0.y = pkbf(p[2].y, p[3].y);
                w0.z = pkbf(p[4].y, p[5].y);  w0.w = pkbf(p[6].y, p[7].y);
                w1.x = pkbf(p[8].y, p[9].y);  w1.y = pkbf(p[10].y, p[11].y);
                w1.z = pkbf(p[12].y, p[13].y); w1.w = pkbf(p[14].y, p[15].y);
            }
            *reinterpret_cast<uint4*>(lB + loff(cp + c, kq * 2)) = w0;
            *reinterpret_cast<uint4*>(lB + loff(cp + c, kq * 2 + 16)) = w1;
        }
    };
    auto compute = [&](const char* base) {
        const char* lA = base;
        const char* lB = base + TILEB;
#pragma unroll
        for (int s = 0; s < 2; ++s) {
            short8 af[4], bf[4];
#pragma unroll
            for (int m = 0; m < 4; ++m)
                af[m] = *reinterpret_cast<const short8*>(
                    lA + loff(wr + m * 16 + fr, s * 64 + kb));
#pragma unroll
            for (int n = 0; n < 4; ++n)
                bf[n] = *reinterpret_cast<const short8*>(
                    lB + loff(wc + n * 16 + fr, s * 64 + kb));
#pragma unroll
            for (int m = 0; m < 4; ++m)
#pragma unroll
                for (int n = 0; n < 4; ++n)
                    acc[m][n] = __builtin_amdgcn_mfma_f32_16x16x32_bf16(
                        af[m], bf[n], acc[m][n], 0, 0, 0);
        }
    };

    f32x4 paX[8], paY[8];
    float2 pbX[16], pbY[16];

    // ---- prologue: tile0 -> X -> buf0; issue tile1 -> Y ----
    load_t(paX, pbX, kstart);
    write_t(lds[0], paX, pbX);
    if (nt > 1) load_t(paY, pbY, kstart + KSTEP);

    // ---- main loop, 2-step unrolled (static X/Y, static buf parity) ----
    for (int t = 0; t < nt; t += 2) {
        {   // even step: compute buf0; write Y->buf1; load X<-t+2
            __syncthreads();
            if (t + 1 < nt) write_t(lds[1], paY, pbY);
            if (t + 2 < nt) load_t(paX, pbX, kstart + (t + 2) * KSTEP);
            compute(lds[0]);
        }
        if (t + 1 < nt) {  // odd step: compute buf1; write X->buf0; load Y
            __syncthreads();
            if (t + 2 < nt) write_t(lds[0], paX, pbX);
            if (t + 3 < nt) load_t(paY, pbY, kstart + (t + 3) * KSTEP);
            compute(lds[1]);
        }
    }

    // ---- epilogue: atomic accumulate (C pre-zeroed); mask row<=col ----
    // C/D layout: col=lane&15, row=(lane>>4)*4+reg
#pragma unroll
    for (int m = 0; m < 4; ++m) {
        const int rbase = row0 + wr + m * 16 + (lane >> 4) * 4;
#pragma unroll
        for (int n = 0; n < 4; ++n) {
            const int col = col0 + wc + n * 16 + fr;
#pragma unroll
            for (int r = 0; r < 4; ++r) {
                const int row = rbase + r;
                if (row <= col)
                    unsafeAtomicAdd(&C[(size_t)row * NDIM + col],
                                    acc[m][n][r]);
            }
        }
    }
}

extern "C" void kernel_launch(void* const* d_in, const int* in_sizes, int n_in,
                              void* d_out, int out_size, void* d_ws,
                              size_t ws_size, hipStream_t stream) {
    const float* A = (const float*)d_in[0];
    const float* B = (const float*)d_in[1];
    float* C = (float*)d_out;
    zero_c_kernel<<<dim3(2048), dim3(256), 0, stream>>>(C);
    trimm_split_kernel<<<dim3(NSUB), dim3(256), 0, stream>>>(A, B, C);
}

// Round 11
// 132.335 us; speedup vs baseline: 1.2536x; 1.2536x over previous
//
#include <hip/hip_runtime.h>
#include <hip/hip_bf16.h>

// C = triu( triu(A) @ triu(B) ), N=4096, fp32 in/out.
// Two-pass: (1) prep: zero ALL of C + convert fp32->bf16 into TILED
// FRAGMENT-ORDER subtiles in d_ws ([g:4][row:128][16B] per 128x32 subtile,
// triangular halves only); (2) main: m97-style GEMM — global_load_lds direct
// staging (linear, matches stored layout), ds_read_b128 fragment reads
// (2-way banks = free), 16 MFMA/step, one barrier/step, split-K + atomics.
// R10 bug fixed: zero pass now covers all 4096 rows (was 1024 -> poison
// survived in rows>=1024 and atomics accumulated across graph replays).

#define NDIM 4096
#define NBLK 32
#define SUBT_B 8192                        // one 128x32 bf16 subtile
#define NSUBT 2112                         // packed subtiles per matrix
#define WS_A ((size_t)NSUBT * SUBT_B)      // 17,301,504
#define WS_TOTAL (2 * WS_A)                // 34,603,008
#define NSUB 1704                          // split-K blocks (chunk = 512 k)
#define CHUNK 512

typedef __attribute__((ext_vector_type(8))) short short8;
typedef __attribute__((ext_vector_type(4))) float f32x4;

__device__ __forceinline__ unsigned pkbf(float a, float b) {
    __hip_bfloat162 h = __float22bfloat162_rn(make_float2(a, b));
    unsigned r;
    __builtin_memcpy(&r, &h, sizeof(r));
    return r;
}

__device__ __forceinline__ void gll16(const void* g, void* l) {
    __builtin_amdgcn_global_load_lds(
        (const __attribute__((address_space(1))) unsigned int*)g,
        (__attribute__((address_space(3))) unsigned int*)l, 16, 0, 0);
}

__device__ __forceinline__ int offA(int bi) { return 130 * bi - 2 * bi * bi; }
__device__ __forceinline__ int offB(int bj) { return 2 * bj * (bj + 1); }

// ---------------- pass 1: zero C + convert/tile A and B ----------------
__global__ __launch_bounds__(256) void prep_kernel(
    const float* __restrict__ A, const float* __restrict__ B,
    float* __restrict__ C, char* __restrict__ ws) {
    const int t = threadIdx.x;
    int b = blockIdx.x;

    if (b < 1024) {  // ---- zero ALL of C: 1024 blocks x 4096 float4 ----
        const float4 z = make_float4(0.f, 0.f, 0.f, 0.f);
        float4* C4 = reinterpret_cast<float4*>(C);
#pragma unroll
        for (int j = 0; j < 16; ++j)
            C4[(size_t)b * 4096 + j * 256 + t] = z;
        return;
    }
    b -= 1024;

    if (b < NSUBT) {  // ---- A subtile: [row][k] fp32 -> [g][row][16B] bf16 ----
        int bi = 0, rem = b;
        while (rem >= 128 - 4 * bi) { rem -= 128 - 4 * bi; ++bi; }
        const int kt32 = 4 * bi + rem;

        __shared__ __align__(16) char lsub[SUBT_B];
        const float* src = A + (size_t)(bi * 128) * NDIM + kt32 * 32;
#pragma unroll
        for (int j = 0; j < 4; ++j) {
            const int s4 = t + 256 * j;          // 0..1023 float4 chunks
            const int row = s4 >> 3;
            const int kf = (s4 & 7) * 4;         // float offset in 32-k row
            const float4 v =
                *reinterpret_cast<const float4*>(src + (size_t)row * NDIM + kf);
            uint2 w;
            w.x = pkbf(v.x, v.y);
            w.y = pkbf(v.z, v.w);
            *reinterpret_cast<uint2*>(lsub + (kf >> 3) * 2048 + row * 16 +
                                      (kf & 4) * 2) = w;
        }
        __syncthreads();
        char* dst = ws + (size_t)b * SUBT_B;
#pragma unroll
        for (int j = 0; j < 2; ++j) {
            const int d = t + 256 * j;           // 0..511 16B chunks
            *reinterpret_cast<uint4*>(dst + d * 16) =
                *reinterpret_cast<const uint4*>(lsub + d * 16);
        }
        return;
    }
    b -= NSUBT;

    {  // ---- B subtile: transpose [k][col] fp32 -> [g][col][16B] bf16 ----
        int bj = 0, rem = b;
        while (rem >= 4 * (bj + 1)) { rem -= 4 * (bj + 1); ++bj; }
        const int kt32 = rem;

        const int c = t & 127;
        const int kq = (t >> 7) * 16;            // k-offset 0 or 16
        const float* src = B + (size_t)(kt32 * 32 + kq) * NDIM + bj * 128 + c;
        float v[16];
#pragma unroll
        for (int i = 0; i < 16; ++i) v[i] = src[(size_t)i * NDIM];

        uint4 w0, w1;
        w0.x = pkbf(v[0], v[1]);   w0.y = pkbf(v[2], v[3]);
        w0.z = pkbf(v[4], v[5]);   w0.w = pkbf(v[6], v[7]);
        w1.x = pkbf(v[8], v[9]);   w1.y = pkbf(v[10], v[11]);
        w1.z = pkbf(v[12], v[13]); w1.w = pkbf(v[14], v[15]);

        char* dst = ws + WS_A + (size_t)b * SUBT_B + c * 16;
        const int g0 = kq >> 3;                  // 0 or 2
        *reinterpret_cast<uint4*>(dst + g0 * 2048) = w0;
        *reinterpret_cast<uint4*>(dst + (g0 + 1) * 2048) = w1;
    }
}

// ---------------- pass 2: MFMA GEMM from tiled bf16 ws ----------------
__global__ __launch_bounds__(256) void trimm_main_kernel(
    const char* __restrict__ ws, float* __restrict__ C) {
    const int tid = threadIdx.x;

    // decode sub-block -> (bi, bj, ch), longest k-range first
    int bi, bj, ch;
    {
        int r = blockIdx.x;
        int L = NBLK;
        for (;;) {
            const int cpt = (L + 3) >> 2;        // ceil(L/4) chunks per tile
            const int cnt = (NBLK + 1 - L) * cpt;
            if (r < cnt) {
                bi = r / cpt;
                ch = r - bi * cpt;
                bj = bi + L - 1;
                break;
            }
            r -= cnt;
            --L;
        }
    }

    const int row0 = bi * 128;
    const int col0 = bj * 128;
    const int kstart = row0 + ch * CHUNK;
    const int kend = min(col0 + 128, kstart + CHUNK);
    const int nt = (kend - kstart) >> 5;         // 1..16 BK=32 steps

    const int kt0 = kstart >> 5;
    const char* asub = ws + (size_t)(offA(bi) + kt0 - 4 * bi) * SUBT_B;
    const char* bsub = ws + WS_A + (size_t)(offB(bj) + kt0) * SUBT_B;

    __shared__ __align__(16) char lds[2][2][SUBT_B];   // [buf][A|B] 32 KB

    f32x4 acc[4][4];
    const f32x4 fz = {0.f, 0.f, 0.f, 0.f};
#pragma unroll
    for (int m = 0; m < 4; ++m)
#pragma unroll
        for (int n = 0; n < 4; ++n) acc[m][n] = fz;

    const int wv = tid >> 6;
    const int wr = (wv >> 1) * 64;
    const int wc = (wv & 1) * 64;
    const int lane = tid & 63;
    const int fr = lane & 15;
    const int gof = (lane >> 4) * 2048;          // k-group byte offset

    auto stage = [&](int buf, int t) {
#pragma unroll
        for (int q = 0; q < 2; ++q) {
            const int c = wv * 2 + q;            // wave's 1KB chunks (0..7)
            gll16(asub + (size_t)t * SUBT_B + c * 1024 + lane * 16,
                  &lds[buf][0][c * 1024]);
            gll16(bsub + (size_t)t * SUBT_B + c * 1024 + lane * 16,
                  &lds[buf][1][c * 1024]);
        }
    };
    auto compute = [&](int buf) {
        const char* A_ = &lds[buf][0][0];
        const char* B_ = &lds[buf][1][0];
        short8 af[4], bf[4];
#pragma unroll
        for (int m = 0; m < 4; ++m)
            af[m] = *reinterpret_cast<const short8*>(
                A_ + gof + (wr + m * 16 + fr) * 16);
#pragma unroll
        for (int n = 0; n < 4; ++n)
            bf[n] = *reinterpret_cast<const short8*>(
                B_ + gof + (wc + n * 16 + fr) * 16);
#pragma unroll
        for (int m = 0; m < 4; ++m)
#pragma unroll
            for (int n = 0; n < 4; ++n)
                acc[m][n] = __builtin_amdgcn_mfma_f32_16x16x32_bf16(
                    af[m], bf[n], acc[m][n], 0, 0, 0);
    };

    stage(0, 0);
    int cur = 0;
    for (int t = 0; t < nt; ++t) {
        __syncthreads();                 // drains vmcnt -> buf[cur] ready
        if (t + 1 < nt) stage(cur ^ 1, t + 1);   // in flight a FULL step
        compute(cur);
        cur ^= 1;
    }

    // epilogue: atomic accumulate (C pre-zeroed); mask row<=col
#pragma unroll
    for (int m = 0; m < 4; ++m) {
        const int rbase = row0 + wr + m * 16 + (lane >> 4) * 4;
#pragma unroll
        for (int n = 0; n < 4; ++n) {
            const int col = col0 + wc + n * 16 + fr;
#pragma unroll
            for (int r = 0; r < 4; ++r) {
                const int row = rbase + r;
                if (row <= col)
                    unsafeAtomicAdd(&C[(size_t)row * NDIM + col],
                                    acc[m][n][r]);
            }
        }
    }
}

// ---------------- fallback (proven R3 kernel, no workspace) ----------------
#define FLSTR 80
__device__ __forceinline__ int floff(int row, int kb) { return row * FLSTR + kb; }

__global__ __launch_bounds__(256) void trimm_fallback_kernel(
    const float* __restrict__ A, const float* __restrict__ B,
    float* __restrict__ C) {
    const int tid = threadIdx.x;
    const int id = blockIdx.x;
    int bi, bj;
    if (id >= 528) {
        int r = id - 528;
        int p = 1;
        while (r >= p) { r -= p; ++p; }
        bi = p; bj = r;
        const size_t base = (size_t)bi * 128 * NDIM + (size_t)bj * 128;
        const float4 z = make_float4(0.f, 0.f, 0.f, 0.f);
#pragma unroll
        for (int t = 0; t < 16; ++t) {
            const int f = tid + 256 * t;
            *reinterpret_cast<float4*>(
                &C[base + (size_t)(f >> 5) * NDIM + (f & 31) * 4]) = z;
        }
        return;
    }
    {
        int r = id, L = NBLK;
        while (r >= NBLK + 1 - L) { r -= NBLK + 1 - L; --L; }
        bi = r; bj = bi + L - 1;
    }
    const int row0 = bi * 128, col0 = bj * 128;
    __shared__ __align__(16) char lAs[128 * FLSTR];
    __shared__ __align__(16) char lBs[128 * FLSTR];
    f32x4 acc[4][4];
    const f32x4 fz = {0.f, 0.f, 0.f, 0.f};
#pragma unroll
    for (int m = 0; m < 4; ++m)
#pragma unroll
        for (int n = 0; n < 4; ++n) acc[m][n] = fz;
    const int wv = tid >> 6, wr = (wv >> 1) * 64, wc = (wv & 1) * 64;
    const int lane = tid & 63, fr = lane & 15, kb = (lane >> 4) * 16;
    const int bn = tid & 127, bkh = (tid >> 7) * 16;
    const int kendf = col0 + 128;
    for (int kt = row0; kt < kendf; kt += 32) {
        __syncthreads();
#pragma unroll
        for (int j = 0; j < 4; ++j) {
            const int f = tid + 256 * j;
            const int rr = f >> 3, kq = (f & 7) * 4;
            const float4 v = *reinterpret_cast<const float4*>(
                &A[(size_t)(row0 + rr) * NDIM + kt + kq]);
            uint2 w;
            w.x = pkbf(v.x, v.y); w.y = pkbf(v.z, v.w);
            *reinterpret_cast<uint2*>(lAs + floff(rr, kq * 2)) = w;
        }
        {
            float tv[16];
#pragma unroll
            for (int kk = 0; kk < 16; ++kk)
                tv[kk] = B[(size_t)(kt + bkh + kk) * NDIM + col0 + bn];
            uint4 w0, w1;
            w0.x = pkbf(tv[0], tv[1]);   w0.y = pkbf(tv[2], tv[3]);
            w0.z = pkbf(tv[4], tv[5]);   w0.w = pkbf(tv[6], tv[7]);
            w1.x = pkbf(tv[8], tv[9]);   w1.y = pkbf(tv[10], tv[11]);
            w1.z = pkbf(tv[12], tv[13]); w1.w = pkbf(tv[14], tv[15]);
            *reinterpret_cast<uint4*>(lBs + floff(bn, bkh * 2)) = w0;
            *reinterpret_cast<uint4*>(lBs + floff(bn, bkh * 2 + 16)) = w1;
        }
        __syncthreads();
        short8 af[4], bf[4];
#pragma unroll
        for (int m = 0; m < 4; ++m)
            af[m] = *reinterpret_cast<const short8*>(
                lAs + floff(wr + m * 16 + fr, kb));
#pragma unroll
        for (int n = 0; n < 4; ++n)
            bf[n] = *reinterpret_cast<const short8*>(
                lBs + floff(wc + n * 16 + fr, kb));
#pragma unroll
        for (int m = 0; m < 4; ++m)
#pragma unroll
            for (int n = 0; n < 4; ++n)
                acc[m][n] = __builtin_amdgcn_mfma_f32_16x16x32_bf16(
                    af[m], bf[n], acc[m][n], 0, 0, 0);
    }
#pragma unroll
    for (int m = 0; m < 4; ++m) {
        const int rbase = row0 + wr + m * 16 + (lane >> 4) * 4;
#pragma unroll
        for (int n = 0; n < 4; ++n) {
            const int col = col0 + wc + n * 16 + fr;
#pragma unroll
            for (int r = 0; r < 4; ++r) {
                const int row = rbase + r;
                C[(size_t)row * NDIM + col] = (row <= col) ? acc[m][n][r] : 0.f;
            }
        }
    }
}

extern "C" void kernel_launch(void* const* d_in, const int* in_sizes, int n_in,
                              void* d_out, int out_size, void* d_ws,
                              size_t ws_size, hipStream_t stream) {
    const float* A = (const float*)d_in[0];
    const float* B = (const float*)d_in[1];
    float* C = (float*)d_out;
    if (ws_size < WS_TOTAL) {
        trimm_fallback_kernel<<<dim3(1024), dim3(256), 0, stream>>>(A, B, C);
        return;
    }
    char* ws = (char*)d_ws;
    prep_kernel<<<dim3(1024 + 2 * NSUBT), dim3(256), 0, stream>>>(A, B, C, ws);
    trimm_main_kernel<<<dim3(NSUB), dim3(256), 0, stream>>>(ws, C);
}

// Round 12
// 85.139 us; speedup vs baseline: 1.9485x; 1.5543x over previous
//
#include <hip/hip_runtime.h>
#include <hip/hip_bf16.h>

// C = triu( triu(A) @ triu(B) ), N=4096, fp32 in/out.
// Pass 1 (prep): zero strictly-lower tiles of C + convert fp32->bf16 into
// TILED FRAGMENT-ORDER subtiles in d_ws ([g:4][row:128][16B] per 128x32
// subtile, triangular halves only).
// Pass 2 (main): one block per upper tile (528, longest-K first), m97-style
// loop with global_load_lds direct staging from the fragment-ordered ws,
// 3-buffer LDS pipeline + COUNTED vmcnt(4) (stage t's loads issued 2 full
// steps earlier -> wait is ~free), 16 MFMA/step, direct masked stores
// (no atomics -> deterministic, no L2 atomic serialization).

#define NDIM 4096
#define NBLK 32
#define SUBT_B 8192                        // one 128x32 bf16 subtile
#define NSUBT 2112                         // packed subtiles per matrix
#define WS_A ((size_t)NSUBT * SUBT_B)      // 17,301,504
#define WS_TOTAL (2 * WS_A)                // 34,603,008
#define NZERO 496                          // strictly-lower 128x128 tiles

typedef __attribute__((ext_vector_type(8))) short short8;
typedef __attribute__((ext_vector_type(4))) float f32x4;

__device__ __forceinline__ unsigned pkbf(float a, float b) {
    __hip_bfloat162 h = __float22bfloat162_rn(make_float2(a, b));
    unsigned r;
    __builtin_memcpy(&r, &h, sizeof(r));
    return r;
}

__device__ __forceinline__ void gll16(const void* g, void* l) {
    __builtin_amdgcn_global_load_lds(
        (const __attribute__((address_space(1))) unsigned int*)g,
        (__attribute__((address_space(3))) unsigned int*)l, 16, 0, 0);
}

__device__ __forceinline__ int offA(int bi) { return 130 * bi - 2 * bi * bi; }
__device__ __forceinline__ int offB(int bj) { return 2 * bj * (bj + 1); }

// ---------------- pass 1: zero lower tiles + convert/tile A and B ----------
__global__ __launch_bounds__(256) void prep_kernel(
    const float* __restrict__ A, const float* __restrict__ B,
    float* __restrict__ C, char* __restrict__ ws) {
    const int t = threadIdx.x;
    int b = blockIdx.x;

    if (b < NZERO) {  // ---- zero one strictly-lower 128x128 tile ----
        int r = b, p = 1;
        while (r >= p) { r -= p; ++p; }
        const int bi = p, bj = r;          // bj < bi
        const size_t base = (size_t)bi * 128 * NDIM + (size_t)bj * 128;
        const float4 z = make_float4(0.f, 0.f, 0.f, 0.f);
#pragma unroll
        for (int j = 0; j < 16; ++j) {
            const int f = t + 256 * j;     // 0..4095 float4 chunks
            *reinterpret_cast<float4*>(
                &C[base + (size_t)(f >> 5) * NDIM + (f & 31) * 4]) = z;
        }
        return;
    }
    b -= NZERO;

    if (b < NSUBT) {  // ---- A subtile: [row][k] fp32 -> [g][row][16B] bf16 ----
        int bi = 0, rem = b;
        while (rem >= 128 - 4 * bi) { rem -= 128 - 4 * bi; ++bi; }
        const int kt32 = 4 * bi + rem;

        __shared__ __align__(16) char lsub[SUBT_B];
        const float* src = A + (size_t)(bi * 128) * NDIM + kt32 * 32;
#pragma unroll
        for (int j = 0; j < 4; ++j) {
            const int s4 = t + 256 * j;          // 0..1023 float4 chunks
            const int row = s4 >> 3;
            const int kf = (s4 & 7) * 4;         // float offset in 32-k row
            const float4 v =
                *reinterpret_cast<const float4*>(src + (size_t)row * NDIM + kf);
            uint2 w;
            w.x = pkbf(v.x, v.y);
            w.y = pkbf(v.z, v.w);
            *reinterpret_cast<uint2*>(lsub + (kf >> 3) * 2048 + row * 16 +
                                      (kf & 4) * 2) = w;
        }
        __syncthreads();
        char* dst = ws + (size_t)b * SUBT_B;
#pragma unroll
        for (int j = 0; j < 2; ++j) {
            const int d = t + 256 * j;           // 0..511 16B chunks
            *reinterpret_cast<uint4*>(dst + d * 16) =
                *reinterpret_cast<const uint4*>(lsub + d * 16);
        }
        return;
    }
    b -= NSUBT;

    {  // ---- B subtile: transpose [k][col] fp32 -> [g][col][16B] bf16 ----
        int bj = 0, rem = b;
        while (rem >= 4 * (bj + 1)) { rem -= 4 * (bj + 1); ++bj; }
        const int kt32 = rem;

        const int c = t & 127;
        const int kq = (t >> 7) * 16;            // k-offset 0 or 16
        const float* src = B + (size_t)(kt32 * 32 + kq) * NDIM + bj * 128 + c;
        float v[16];
#pragma unroll
        for (int i = 0; i < 16; ++i) v[i] = src[(size_t)i * NDIM];

        uint4 w0, w1;
        w0.x = pkbf(v[0], v[1]);   w0.y = pkbf(v[2], v[3]);
        w0.z = pkbf(v[4], v[5]);   w0.w = pkbf(v[6], v[7]);
        w1.x = pkbf(v[8], v[9]);   w1.y = pkbf(v[10], v[11]);
        w1.z = pkbf(v[12], v[13]); w1.w = pkbf(v[14], v[15]);

        char* dst = ws + WS_A + (size_t)b * SUBT_B + c * 16;
        const int g0 = kq >> 3;                  // 0 or 2
        *reinterpret_cast<uint4*>(dst + g0 * 2048) = w0;
        *reinterpret_cast<uint4*>(dst + (g0 + 1) * 2048) = w1;
    }
}

// ---------------- pass 2: MFMA GEMM, one block per upper tile ----------------
__global__ __launch_bounds__(256) void trimm_main_kernel(
    const char* __restrict__ ws, float* __restrict__ C) {
    const int tid = threadIdx.x;

    // decode upper tile, longest k-range first
    int bi, bj;
    {
        int r = blockIdx.x, L = NBLK;
        while (r >= NBLK + 1 - L) { r -= NBLK + 1 - L; --L; }
        bi = r;
        bj = bi + L - 1;
    }

    const int row0 = bi * 128;
    const int col0 = bj * 128;
    const int nt = (col0 + 128 - row0) >> 5;     // 4..128 BK=32 steps

    const char* asub = ws + (size_t)offA(bi) * SUBT_B;
    const char* bsub = ws + WS_A + (size_t)(offB(bj) + 4 * bi) * SUBT_B;

    __shared__ __align__(16) char lds[3][2][SUBT_B];   // 48 KB, 3 blocks/CU

    f32x4 acc[4][4];
    const f32x4 fz = {0.f, 0.f, 0.f, 0.f};
#pragma unroll
    for (int m = 0; m < 4; ++m)
#pragma unroll
        for (int n = 0; n < 4; ++n) acc[m][n] = fz;

    const int wv = tid >> 6;
    const int wr = (wv >> 1) * 64;
    const int wc = (wv & 1) * 64;
    const int lane = tid & 63;
    const int fr = lane & 15;
    const int gof = (lane >> 4) * 2048;          // k-group byte offset

    auto stage = [&](int buf, int t) {           // 4 gll16 per wave
#pragma unroll
        for (int q = 0; q < 2; ++q) {
            const int c = wv * 2 + q;            // wave's 1KB chunks (0..7)
            gll16(asub + (size_t)t * SUBT_B + c * 1024 + lane * 16,
                  &lds[buf][0][c * 1024]);
            gll16(bsub + (size_t)t * SUBT_B + c * 1024 + lane * 16,
                  &lds[buf][1][c * 1024]);
        }
    };
    auto compute = [&](int buf) {
        const char* A_ = &lds[buf][0][0];
        const char* B_ = &lds[buf][1][0];
        short8 af[4], bf[4];
#pragma unroll
        for (int m = 0; m < 4; ++m)
            af[m] = *reinterpret_cast<const short8*>(
                A_ + gof + (wr + m * 16 + fr) * 16);
#pragma unroll
        for (int n = 0; n < 4; ++n)
            bf[n] = *reinterpret_cast<const short8*>(
                B_ + gof + (wc + n * 16 + fr) * 16);
#pragma unroll
        for (int m = 0; m < 4; ++m)
#pragma unroll
            for (int n = 0; n < 4; ++n)
                acc[m][n] = __builtin_amdgcn_mfma_f32_16x16x32_bf16(
                    af[m], bf[n], acc[m][n], 0, 0, 0);
    };

    // ---- 3-buffer pipeline, counted vmcnt: stage t completes ~2 steps
    //      after issue; vmcnt(4) leaves stage t+1's 4 loads in flight ----
    stage(0, 0);
    if (nt > 1) stage(1, 1);
    for (int t = 0; t < nt; ++t) {
        if (t + 1 < nt)
            asm volatile("s_waitcnt vmcnt(4)" ::: "memory");
        else
            asm volatile("s_waitcnt vmcnt(0)" ::: "memory");
        __builtin_amdgcn_s_barrier();   // all waves: stage(t) done,
                                        // compute(t-1) finished everywhere
        if (t + 2 < nt) stage((t + 2) % 3, t + 2);  // into freed buffer
        compute(t % 3);
    }

    // ---- epilogue: direct masked stores (full tile incl. zeros) ----
    // C/D layout: col=lane&15, row=(lane>>4)*4+reg
#pragma unroll
    for (int m = 0; m < 4; ++m) {
        const int rbase = row0 + wr + m * 16 + (lane >> 4) * 4;
#pragma unroll
        for (int n = 0; n < 4; ++n) {
            const int col = col0 + wc + n * 16 + fr;
#pragma unroll
            for (int r = 0; r < 4; ++r) {
                const int row = rbase + r;
                C[(size_t)row * NDIM + col] = (row <= col) ? acc[m][n][r] : 0.f;
            }
        }
    }
}

// ---------------- fallback (proven R3 kernel, no workspace) ----------------
#define FLSTR 80
__device__ __forceinline__ int floff(int row, int kb) { return row * FLSTR + kb; }

__global__ __launch_bounds__(256) void trimm_fallback_kernel(
    const float* __restrict__ A, const float* __restrict__ B,
    float* __restrict__ C) {
    const int tid = threadIdx.x;
    const int id = blockIdx.x;
    int bi, bj;
    if (id >= 528) {
        int r = id - 528;
        int p = 1;
        while (r >= p) { r -= p; ++p; }
        bi = p; bj = r;
        const size_t base = (size_t)bi * 128 * NDIM + (size_t)bj * 128;
        const float4 z = make_float4(0.f, 0.f, 0.f, 0.f);
#pragma unroll
        for (int t = 0; t < 16; ++t) {
            const int f = tid + 256 * t;
            *reinterpret_cast<float4*>(
                &C[base + (size_t)(f >> 5) * NDIM + (f & 31) * 4]) = z;
        }
        return;
    }
    {
        int r = id, L = NBLK;
        while (r >= NBLK + 1 - L) { r -= NBLK + 1 - L; --L; }
        bi = r; bj = bi + L - 1;
    }
    const int row0 = bi * 128, col0 = bj * 128;
    __shared__ __align__(16) char lAs[128 * FLSTR];
    __shared__ __align__(16) char lBs[128 * FLSTR];
    f32x4 acc[4][4];
    const f32x4 fz = {0.f, 0.f, 0.f, 0.f};
#pragma unroll
    for (int m = 0; m < 4; ++m)
#pragma unroll
        for (int n = 0; n < 4; ++n) acc[m][n] = fz;
    const int wv = tid >> 6, wr = (wv >> 1) * 64, wc = (wv & 1) * 64;
    const int lane = tid & 63, fr = lane & 15, kb = (lane >> 4) * 16;
    const int bn = tid & 127, bkh = (tid >> 7) * 16;
    const int kendf = col0 + 128;
    for (int kt = row0; kt < kendf; kt += 32) {
        __syncthreads();
#pragma unroll
        for (int j = 0; j < 4; ++j) {
            const int f = tid + 256 * j;
            const int rr = f >> 3, kq = (f & 7) * 4;
            const float4 v = *reinterpret_cast<const float4*>(
                &A[(size_t)(row0 + rr) * NDIM + kt + kq]);
            uint2 w;
            w.x = pkbf(v.x, v.y); w.y = pkbf(v.z, v.w);
            *reinterpret_cast<uint2*>(lAs + floff(rr, kq * 2)) = w;
        }
        {
            float tv[16];
#pragma unroll
            for (int kk = 0; kk < 16; ++kk)
                tv[kk] = B[(size_t)(kt + bkh + kk) * NDIM + col0 + bn];
            uint4 w0, w1;
            w0.x = pkbf(tv[0], tv[1]);   w0.y = pkbf(tv[2], tv[3]);
            w0.z = pkbf(tv[4], tv[5]);   w0.w = pkbf(tv[6], tv[7]);
            w1.x = pkbf(tv[8], tv[9]);   w1.y = pkbf(tv[10], tv[11]);
            w1.z = pkbf(tv[12], tv[13]); w1.w = pkbf(tv[14], tv[15]);
            *reinterpret_cast<uint4*>(lBs + floff(bn, bkh * 2)) = w0;
            *reinterpret_cast<uint4*>(lBs + floff(bn, bkh * 2 + 16)) = w1;
        }
        __syncthreads();
        short8 af[4], bf[4];
#pragma unroll
        for (int m = 0; m < 4; ++m)
            af[m] = *reinterpret_cast<const short8*>(
                lAs + floff(wr + m * 16 + fr, kb));
#pragma unroll
        for (int n = 0; n < 4; ++n)
            bf[n] = *reinterpret_cast<const short8*>(
                lBs + floff(wc + n * 16 + fr, kb));
#pragma unroll
        for (int m = 0; m < 4; ++m)
#pragma unroll
            for (int n = 0; n < 4; ++n)
                acc[m][n] = __builtin_amdgcn_mfma_f32_16x16x32_bf16(
                    af[m], bf[n], acc[m][n], 0, 0, 0);
    }
#pragma unroll
    for (int m = 0; m < 4; ++m) {
        const int rbase = row0 + wr + m * 16 + (lane >> 4) * 4;
#pragma unroll
        for (int n = 0; n < 4; ++n) {
            const int col = col0 + wc + n * 16 + fr;
#pragma unroll
            for (int r = 0; r < 4; ++r) {
                const int row = rbase + r;
                C[(size_t)row * NDIM + col] = (row <= col) ? acc[m][n][r] : 0.f;
            }
        }
    }
}

extern "C" void kernel_launch(void* const* d_in, const int* in_sizes, int n_in,
                              void* d_out, int out_size, void* d_ws,
                              size_t ws_size, hipStream_t stream) {
    const float* A = (const float*)d_in[0];
    const float* B = (const float*)d_in[1];
    float* C = (float*)d_out;
    if (ws_size < WS_TOTAL) {
        trimm_fallback_kernel<<<dim3(1024), dim3(256), 0, stream>>>(A, B, C);
        return;
    }
    char* ws = (char*)d_ws;
    prep_kernel<<<dim3(NZERO + 2 * NSUBT), dim3(256), 0, stream>>>(A, B, C, ws);
    trimm_main_kernel<<<dim3(528), dim3(256), 0, stream>>>(ws, C);
}